// Round 1
// baseline (685.211 us; speedup 1.0000x reference)
//
#include <hip/hip_runtime.h>

#define N_NODES 100000
#define N_EDGES 1250000
#define IN_D 128
#define OUT_D 64
#define BSHIFT 7                                  // 128 nodes per bucket
#define NBUCK  782                                // ceil(100000/128)
#define CAP    2560                               // mean 1600 + 24 sigma
#define EPB    4096                               // edges per passA block
#define NBLK_E 306                                // ceil(1250000/4096)
#define NBLK_G 1563                               // ceil(6250 node-tiles / 4)

typedef __attribute__((ext_vector_type(8))) __bf16 bf16x8;
typedef __attribute__((ext_vector_type(4))) float floatx4;

__device__ __forceinline__ float2 up2(unsigned u) {   // 2 bf16 -> 2 f32
    return make_float2(__uint_as_float(u << 16),
                       __uint_as_float(u & 0xFFFF0000u));
}

// ---- Kernel A (fused): blocks [0,306): passA bucket scatter (int4 MLP,
//      fixed-capacity buckets, payload {src|(d&127)<<17, tc*edge_d}).
//      blocks [306,...): node_proj MFMA GEMM, vectorized in-reg W swizzle. ----
__global__ __launch_bounds__(256) void fusedA_kernel(
    const float* __restrict__ x, const float* __restrict__ W1,
    const float* __restrict__ W2, const float* __restrict__ W0,
    const float* __restrict__ Wa,
    const int* __restrict__ dst, const int* __restrict__ src,
    const float* __restrict__ edge_d,
    int* __restrict__ gcur, uint2* __restrict__ payA,
    unsigned short* __restrict__ zb, unsigned short* __restrict__ zib,
    float* __restrict__ s1, float* __restrict__ s2)
{
    __shared__ __bf16 sB[16384];     // 32 KB (GEMM path)
    __shared__ float  sWa[128];
    __shared__ int    h[NBUCK];      // passA path
    __shared__ int    lcur[NBUCK];

    const int t = threadIdx.x;

    if (blockIdx.x < NBLK_E) {
        // ---------------- passA ----------------
        const float tc = W0[0] * Wa[2 * OUT_D];
        for (int i = t; i < NBUCK; i += 256) h[i] = 0;
        __syncthreads();
        const int base = blockIdx.x * EPB;
        for (int k0 = 0; k0 < EPB; k0 += 1024) {
            int i = base + k0 + t * 4;
            if (i < N_EDGES) {                    // N_EDGES % 4 == 0
                int4 d4 = *(const int4*)(dst + i);
                atomicAdd(&h[d4.x >> BSHIFT], 1);
                atomicAdd(&h[d4.y >> BSHIFT], 1);
                atomicAdd(&h[d4.z >> BSHIFT], 1);
                atomicAdd(&h[d4.w >> BSHIFT], 1);
            }
        }
        __syncthreads();
        for (int b = t; b < NBUCK; b += 256) {
            int hc = h[b];
            int p = hc ? atomicAdd(&gcur[b], hc) : 0;
            lcur[b] = b * CAP + p;
        }
        __syncthreads();
        #define EMIT(dv, sv, ev)                                              \
            { int bk = (dv) >> BSHIFT;                                        \
              int pos = atomicAdd(&lcur[bk], 1);                              \
              if (pos < (bk + 1) * CAP)                                       \
                  payA[pos] = make_uint2((unsigned)(sv) |                     \
                                         ((unsigned)((dv) & 127) << 17),      \
                                         __float_as_uint(tc * (ev))); }
        for (int k0 = 0; k0 < EPB; k0 += 1024) {
            int i = base + k0 + t * 4;
            if (i < N_EDGES) {
                int4   d4 = *(const int4*)(dst + i);
                int4   s4 = *(const int4*)(src + i);
                float4 e4 = *(const float4*)(edge_d + i);
                EMIT(d4.x, s4.x, e4.x);
                EMIT(d4.y, s4.y, e4.y);
                EMIT(d4.z, s4.z, e4.z);
                EMIT(d4.w, s4.w, e4.w);
            }
        }
        #undef EMIT
        return;
    }

    // ------- node_proj: vectorized W swizzle (8 groups/thread) -------
    // group gi = n*16 + k8: read W[n][k8*8 .. +7], write one bf16x8 to the
    // fragment slot ((nt*4+kc)*64 + lane)*8, lane = ((k8&3)<<4)|(n&15).
    #pragma unroll
    for (int g = 0; g < 8; ++g) {
        int gi = t + g * 256;            // 0..2047
        int n  = gi >> 4;
        int k8 = gi & 15;
        const float* wrow = (n < 64) ? (W1 + n * 128) : (W2 + (n - 64) * 128);
        float4 v0 = *(const float4*)(wrow + k8 * 8);
        float4 v1 = *(const float4*)(wrow + k8 * 8 + 4);
        int lane = ((k8 & 3) << 4) | (n & 15);
        int off  = (((n >> 4) * 4 + (k8 >> 2)) * 64 + lane) * 8;
        bf16x8 bb;
        bb[0] = (__bf16)v0.x; bb[1] = (__bf16)v0.y;
        bb[2] = (__bf16)v0.z; bb[3] = (__bf16)v0.w;
        bb[4] = (__bf16)v1.x; bb[5] = (__bf16)v1.y;
        bb[6] = (__bf16)v1.z; bb[7] = (__bf16)v1.w;
        *(bf16x8*)(sB + off) = bb;
    }
    if (t < 128) sWa[t] = Wa[t];
    __syncthreads();

    const int lane = t & 63;
    const int wave = t >> 6;
    const int tile = (blockIdx.x - NBLK_E) * 4 + wave;
    if (tile * 16 >= N_NODES) return;          // 100000 % 16 == 0

    const int n0 = tile * 16;
    const int m  = lane & 15;
    const int kb = lane >> 4;

    floatx4 acc[8];
    #pragma unroll
    for (int q = 0; q < 8; ++q) acc[q] = (floatx4)(0.f);

    const float* xrow = x + (size_t)(n0 + m) * IN_D;

    #pragma unroll
    for (int kc = 0; kc < 4; ++kc) {
        float4 v0 = *(const float4*)(xrow + kc * 32 + kb * 8);
        float4 v1 = *(const float4*)(xrow + kc * 32 + kb * 8 + 4);
        float xs[8] = {v0.x, v0.y, v0.z, v0.w, v1.x, v1.y, v1.z, v1.w};
        bf16x8 ahi, alo;
        #pragma unroll
        for (int j = 0; j < 8; ++j) {
            __bf16 hh = (__bf16)xs[j];
            ahi[j] = hh;
            alo[j] = (__bf16)(xs[j] - (float)hh);
        }
        #pragma unroll
        for (int nt = 0; nt < 8; ++nt) {
            int off = ((nt * 4 + kc) * 64 + lane) * 8;
            bf16x8 b = *(const bf16x8*)(sB + off);
            acc[nt] = __builtin_amdgcn_mfma_f32_16x16x32_bf16(ahi, b, acc[nt], 0, 0, 0);
            acc[nt] = __builtin_amdgcn_mfma_f32_16x16x32_bf16(alo, b, acc[nt], 0, 0, 0);
        }
    }

    // D layout: col = lane&15 (=m), row = kb*4 + reg
    #pragma unroll
    for (int nt = 0; nt < 8; ++nt) {
        int col = (nt & 3) * 16 + m;
        unsigned short* dp = (nt < 4) ? zb : zib;
        #pragma unroll
        for (int reg = 0; reg < 4; ++reg) {
            int row = n0 + kb * 4 + reg;
            __bf16 hh = (__bf16)acc[nt][reg];
            dp[(size_t)row * OUT_D + col] = *(unsigned short*)&hh;
        }
    }

    // s1[n] = z[n,:].Wa[0:64], s2[n] = z[n,:].Wa[64:128]  (fp32 accs)
    #pragma unroll
    for (int reg = 0; reg < 4; ++reg) {
        float p1 = 0.f, p2 = 0.f;
        #pragma unroll
        for (int nt = 0; nt < 4; ++nt) {
            float zv = acc[nt][reg];
            p1 += zv * sWa[nt * 16 + m];
            p2 += zv * sWa[64 + nt * 16 + m];
        }
        #pragma unroll
        for (int off = 8; off > 0; off >>= 1) {
            p1 += __shfl_xor(p1, off);
            p2 += __shfl_xor(p2, off);
        }
        if (m == 0) {
            int row = n0 + kb * 4 + reg;
            s1[row] = p1;
            s2[row] = p2;
        }
    }
}

// ---- Kernel B (accum+finalize): one block per 128-node bucket. Streams the
//      bucket's payA entries once; per edge computes ex = exp(leaky(...)),
//      accumulates den[dl] and num[dl][0:64] via LDS f32 atomics (ds_add_f32),
//      then finalizes out = relu(zi + num/den) in-place. Replaces the old
//      passB (scan+rescatter) + gather kernels and the payB round-trip. ----
__global__ __launch_bounds__(512) void accum_finalize_kernel(
    const int* __restrict__ gcur, const uint2* __restrict__ payA,
    const float* __restrict__ s1, const float* __restrict__ s2,
    const unsigned short* __restrict__ zb, const unsigned short* __restrict__ zib,
    float* __restrict__ out)
{
    __shared__ float num[128][65];   // +1 pad word: bank = (dl + k) % 32
    __shared__ float den[128];
    __shared__ float s2s[128];

    const int b = blockIdx.x, t = threadIdx.x;
    const int n0 = b << BSHIFT;

    for (int i = t; i < 128 * 65; i += 512) (&num[0][0])[i] = 0.f;
    if (t < 128) {
        den[t] = 0.f;
        int node = n0 + t;
        s2s[t] = (node < N_NODES) ? s2[node] : 0.f;
    }
    __syncthreads();

    const int base = b * CAP;
    const int cnt = min(gcur[b], CAP);

    for (int i0 = 0; i0 < cnt; i0 += 512) {
        int i = i0 + t;
        if (i < cnt) {
            uint2 p = payA[base + i];
            int srcn = p.x & 0x1FFFF;
            int dl   = (p.x >> 17) & 127;
            float a  = __uint_as_float(p.y) + s1[srcn] + s2s[dl];
            float e  = (a > 0.f) ? a : 0.01f * a;
            float ex = __expf(e);
            float* nrow = num[dl];
            atomicAdd(&den[dl], ex);
            const uint4* zp = (const uint4*)(zb + (size_t)srcn * OUT_D);
            uint4 q0 = zp[0], q1 = zp[1], q2 = zp[2], q3 = zp[3];
            #define ACC2(w, k) { float2 f = up2(w);                 \
                atomicAdd(nrow + (k),     ex * f.x);                \
                atomicAdd(nrow + (k) + 1, ex * f.y); }
            ACC2(q0.x,  0) ACC2(q0.y,  2) ACC2(q0.z,  4) ACC2(q0.w,  6)
            ACC2(q1.x,  8) ACC2(q1.y, 10) ACC2(q1.z, 12) ACC2(q1.w, 14)
            ACC2(q2.x, 16) ACC2(q2.y, 18) ACC2(q2.z, 20) ACC2(q2.w, 22)
            ACC2(q3.x, 24) ACC2(q3.y, 26) ACC2(q3.z, 28) ACC2(q3.w, 30)
            uint4 q4 = zp[4], q5 = zp[5], q6 = zp[6], q7 = zp[7];
            ACC2(q4.x, 32) ACC2(q4.y, 34) ACC2(q4.z, 36) ACC2(q4.w, 38)
            ACC2(q5.x, 40) ACC2(q5.y, 42) ACC2(q5.z, 44) ACC2(q5.w, 46)
            ACC2(q6.x, 48) ACC2(q6.y, 50) ACC2(q6.z, 52) ACC2(q6.w, 54)
            ACC2(q7.x, 56) ACC2(q7.y, 58) ACC2(q7.z, 60) ACC2(q7.w, 62)
            #undef ACC2
        }
    }
    __syncthreads();

    // finalize: 4 threads per node, 16 dims each
    const int n = t >> 2;
    const int node = n0 + n;
    if (node < N_NODES) {
        const int dq = (t & 3) * 16;
        float dn = den[n];
        float inv = (dn > 0.f) ? 1.f / dn : 0.f;   // empty -> relu(zi)
        const float* nr = &num[n][dq];
        const unsigned short* zr = zib + (size_t)node * OUT_D + dq;
        uint4 z0 = *(const uint4*)zr;
        uint4 z1 = *(const uint4*)(zr + 8);
        float* op = out + (size_t)node * OUT_D + dq;
        float2 f; float4 o;
        f = up2(z0.x); o.x = fmaxf(f.x + nr[ 0]*inv, 0.f); o.y = fmaxf(f.y + nr[ 1]*inv, 0.f);
        f = up2(z0.y); o.z = fmaxf(f.x + nr[ 2]*inv, 0.f); o.w = fmaxf(f.y + nr[ 3]*inv, 0.f);
        ((float4*)op)[0] = o;
        f = up2(z0.z); o.x = fmaxf(f.x + nr[ 4]*inv, 0.f); o.y = fmaxf(f.y + nr[ 5]*inv, 0.f);
        f = up2(z0.w); o.z = fmaxf(f.x + nr[ 6]*inv, 0.f); o.w = fmaxf(f.y + nr[ 7]*inv, 0.f);
        ((float4*)op)[1] = o;
        f = up2(z1.x); o.x = fmaxf(f.x + nr[ 8]*inv, 0.f); o.y = fmaxf(f.y + nr[ 9]*inv, 0.f);
        f = up2(z1.y); o.z = fmaxf(f.x + nr[10]*inv, 0.f); o.w = fmaxf(f.y + nr[11]*inv, 0.f);
        ((float4*)op)[2] = o;
        f = up2(z1.z); o.x = fmaxf(f.x + nr[12]*inv, 0.f); o.y = fmaxf(f.y + nr[13]*inv, 0.f);
        f = up2(z1.w); o.z = fmaxf(f.x + nr[14]*inv, 0.f); o.w = fmaxf(f.y + nr[15]*inv, 0.f);
        ((float4*)op)[3] = o;
    }
}

extern "C" void kernel_launch(void* const* d_in, const int* in_sizes, int n_in,
                              void* d_out, int out_size, void* d_ws, size_t ws_size,
                              hipStream_t stream) {
    const float* node_feats = (const float*)d_in[0];
    const float* edge_d     = (const float*)d_in[1];
    const float* W0         = (const float*)d_in[2];
    const float* W1         = (const float*)d_in[3];
    const float* W2         = (const float*)d_in[4];
    const float* Wa         = (const float*)d_in[5];
    const int*   src        = (const int*)d_in[6];
    const int*   dst        = (const int*)d_in[7];
    float* out = (float*)d_out;

    // workspace layout (~42.5 MB), 16 B aligned sections
    char* ws = (char*)d_ws;
    uint2* payA = (uint2*)ws;    ws += (size_t)NBUCK * CAP * 8;   // 16.0 MB
    unsigned short* zbuf = (unsigned short*)ws; ws += (size_t)N_NODES * OUT_D * 2;
    unsigned short* zib  = (unsigned short*)ws; ws += (size_t)N_NODES * OUT_D * 2;
    float* s1 = (float*)ws;      ws += (size_t)N_NODES * 4;
    float* s2 = (float*)ws;      ws += (size_t)N_NODES * 4;
    int*   gcur = (int*)ws;      ws += ((NBUCK + 3) & ~3) * 4;

    hipMemsetAsync(gcur, 0, NBUCK * 4, stream);

    fusedA_kernel<<<NBLK_E + NBLK_G, 256, 0, stream>>>(
        node_feats, W1, W2, W0, Wa, dst, src, edge_d,
        gcur, payA, zbuf, zib, s1, s2);

    accum_finalize_kernel<<<NBUCK, 512, 0, stream>>>(
        gcur, payA, s1, s2, zbuf, zib, out);
}

// Round 2
// 682.924 us; speedup vs baseline: 1.0033x; 1.0033x over previous
//
#include <hip/hip_runtime.h>

#define N_NODES 100000
#define N_EDGES 1250000
#define IN_D 128
#define OUT_D 64
#define BSHIFT 7                                  // 128 nodes per bucket
#define NBUCK  782                                // ceil(100000/128)
#define CAP    2560                               // mean 1600 + 24 sigma
#define EPB    4096                               // edges per passA block
#define NBLK_E 306                                // ceil(1250000/4096)
#define NBLK_G 1563                               // ceil(6250 node-tiles / 4)

typedef __attribute__((ext_vector_type(8))) __bf16 bf16x8;
typedef __attribute__((ext_vector_type(4))) float floatx4;

__device__ __forceinline__ float2 up2(unsigned u) {   // 2 bf16 -> 2 f32
    return make_float2(__uint_as_float(u << 16),
                       __uint_as_float(u & 0xFFFF0000u));
}

// Hardware LDS float atomic add. hipcc lowers atomicAdd(float*) on shared mem
// to a CAS loop (denormal conformance) -> 544us. ds_add_f32 is fire-and-forget
// (no return), counted by lgkmcnt, drained by __syncthreads before readback.
// Low 32 bits of a generic LDS pointer == LDS byte offset (shared aperture).
__device__ __forceinline__ void lds_fadd(float* p, float v) {
    unsigned a = (unsigned)(size_t)p;
    asm volatile("ds_add_f32 %0, %1" :: "v"(a), "v"(v) : "memory");
}

// ---- Kernel A (fused): blocks [0,306): passA bucket scatter (int4 MLP,
//      fixed-capacity buckets, payload {src|(d&127)<<17, tc*edge_d}).
//      blocks [306,...): node_proj MFMA GEMM, vectorized in-reg W swizzle. ----
__global__ __launch_bounds__(256) void fusedA_kernel(
    const float* __restrict__ x, const float* __restrict__ W1,
    const float* __restrict__ W2, const float* __restrict__ W0,
    const float* __restrict__ Wa,
    const int* __restrict__ dst, const int* __restrict__ src,
    const float* __restrict__ edge_d,
    int* __restrict__ gcur, uint2* __restrict__ payA,
    unsigned short* __restrict__ zb, unsigned short* __restrict__ zib,
    float* __restrict__ s1, float* __restrict__ s2)
{
    __shared__ __bf16 sB[16384];     // 32 KB (GEMM path)
    __shared__ float  sWa[128];
    __shared__ int    h[NBUCK];      // passA path
    __shared__ int    lcur[NBUCK];

    const int t = threadIdx.x;

    if (blockIdx.x < NBLK_E) {
        // ---------------- passA ----------------
        const float tc = W0[0] * Wa[2 * OUT_D];
        for (int i = t; i < NBUCK; i += 256) h[i] = 0;
        __syncthreads();
        const int base = blockIdx.x * EPB;
        for (int k0 = 0; k0 < EPB; k0 += 1024) {
            int i = base + k0 + t * 4;
            if (i < N_EDGES) {                    // N_EDGES % 4 == 0
                int4 d4 = *(const int4*)(dst + i);
                atomicAdd(&h[d4.x >> BSHIFT], 1);
                atomicAdd(&h[d4.y >> BSHIFT], 1);
                atomicAdd(&h[d4.z >> BSHIFT], 1);
                atomicAdd(&h[d4.w >> BSHIFT], 1);
            }
        }
        __syncthreads();
        for (int b = t; b < NBUCK; b += 256) {
            int hc = h[b];
            int p = hc ? atomicAdd(&gcur[b], hc) : 0;
            lcur[b] = b * CAP + p;
        }
        __syncthreads();
        #define EMIT(dv, sv, ev)                                              \
            { int bk = (dv) >> BSHIFT;                                        \
              int pos = atomicAdd(&lcur[bk], 1);                              \
              if (pos < (bk + 1) * CAP)                                       \
                  payA[pos] = make_uint2((unsigned)(sv) |                     \
                                         ((unsigned)((dv) & 127) << 17),      \
                                         __float_as_uint(tc * (ev))); }
        for (int k0 = 0; k0 < EPB; k0 += 1024) {
            int i = base + k0 + t * 4;
            if (i < N_EDGES) {
                int4   d4 = *(const int4*)(dst + i);
                int4   s4 = *(const int4*)(src + i);
                float4 e4 = *(const float4*)(edge_d + i);
                EMIT(d4.x, s4.x, e4.x);
                EMIT(d4.y, s4.y, e4.y);
                EMIT(d4.z, s4.z, e4.z);
                EMIT(d4.w, s4.w, e4.w);
            }
        }
        #undef EMIT
        return;
    }

    // ------- node_proj: vectorized W swizzle (8 groups/thread) -------
    // group gi = n*16 + k8: read W[n][k8*8 .. +7], write one bf16x8 to the
    // fragment slot ((nt*4+kc)*64 + lane)*8, lane = ((k8&3)<<4)|(n&15).
    #pragma unroll
    for (int g = 0; g < 8; ++g) {
        int gi = t + g * 256;            // 0..2047
        int n  = gi >> 4;
        int k8 = gi & 15;
        const float* wrow = (n < 64) ? (W1 + n * 128) : (W2 + (n - 64) * 128);
        float4 v0 = *(const float4*)(wrow + k8 * 8);
        float4 v1 = *(const float4*)(wrow + k8 * 8 + 4);
        int lane = ((k8 & 3) << 4) | (n & 15);
        int off  = (((n >> 4) * 4 + (k8 >> 2)) * 64 + lane) * 8;
        bf16x8 bb;
        bb[0] = (__bf16)v0.x; bb[1] = (__bf16)v0.y;
        bb[2] = (__bf16)v0.z; bb[3] = (__bf16)v0.w;
        bb[4] = (__bf16)v1.x; bb[5] = (__bf16)v1.y;
        bb[6] = (__bf16)v1.z; bb[7] = (__bf16)v1.w;
        *(bf16x8*)(sB + off) = bb;
    }
    if (t < 128) sWa[t] = Wa[t];
    __syncthreads();

    const int lane = t & 63;
    const int wave = t >> 6;
    const int tile = (blockIdx.x - NBLK_E) * 4 + wave;
    if (tile * 16 >= N_NODES) return;          // 100000 % 16 == 0

    const int n0 = tile * 16;
    const int m  = lane & 15;
    const int kb = lane >> 4;

    floatx4 acc[8];
    #pragma unroll
    for (int q = 0; q < 8; ++q) acc[q] = (floatx4)(0.f);

    const float* xrow = x + (size_t)(n0 + m) * IN_D;

    #pragma unroll
    for (int kc = 0; kc < 4; ++kc) {
        float4 v0 = *(const float4*)(xrow + kc * 32 + kb * 8);
        float4 v1 = *(const float4*)(xrow + kc * 32 + kb * 8 + 4);
        float xs[8] = {v0.x, v0.y, v0.z, v0.w, v1.x, v1.y, v1.z, v1.w};
        bf16x8 ahi, alo;
        #pragma unroll
        for (int j = 0; j < 8; ++j) {
            __bf16 hh = (__bf16)xs[j];
            ahi[j] = hh;
            alo[j] = (__bf16)(xs[j] - (float)hh);
        }
        #pragma unroll
        for (int nt = 0; nt < 8; ++nt) {
            int off = ((nt * 4 + kc) * 64 + lane) * 8;
            bf16x8 b = *(const bf16x8*)(sB + off);
            acc[nt] = __builtin_amdgcn_mfma_f32_16x16x32_bf16(ahi, b, acc[nt], 0, 0, 0);
            acc[nt] = __builtin_amdgcn_mfma_f32_16x16x32_bf16(alo, b, acc[nt], 0, 0, 0);
        }
    }

    // D layout: col = lane&15 (=m), row = kb*4 + reg
    #pragma unroll
    for (int nt = 0; nt < 8; ++nt) {
        int col = (nt & 3) * 16 + m;
        unsigned short* dp = (nt < 4) ? zb : zib;
        #pragma unroll
        for (int reg = 0; reg < 4; ++reg) {
            int row = n0 + kb * 4 + reg;
            __bf16 hh = (__bf16)acc[nt][reg];
            dp[(size_t)row * OUT_D + col] = *(unsigned short*)&hh;
        }
    }

    // s1[n] = z[n,:].Wa[0:64], s2[n] = z[n,:].Wa[64:128]  (fp32 accs)
    #pragma unroll
    for (int reg = 0; reg < 4; ++reg) {
        float p1 = 0.f, p2 = 0.f;
        #pragma unroll
        for (int nt = 0; nt < 4; ++nt) {
            float zv = acc[nt][reg];
            p1 += zv * sWa[nt * 16 + m];
            p2 += zv * sWa[64 + nt * 16 + m];
        }
        #pragma unroll
        for (int off = 8; off > 0; off >>= 1) {
            p1 += __shfl_xor(p1, off);
            p2 += __shfl_xor(p2, off);
        }
        if (m == 0) {
            int row = n0 + kb * 4 + reg;
            s1[row] = p1;
            s2[row] = p2;
        }
    }
}

// ---- Kernel B (accum+finalize): one block per 128-node bucket. Streams the
//      bucket's payA entries once; per edge computes ex = exp(leaky(...)),
//      accumulates den[dl] and num[dl][0:64] via hardware ds_add_f32,
//      then finalizes out = relu(zi + num/den) in-place. ----
__global__ __launch_bounds__(512) void accum_finalize_kernel(
    const int* __restrict__ gcur, const uint2* __restrict__ payA,
    const float* __restrict__ s1, const float* __restrict__ s2,
    const unsigned short* __restrict__ zb, const unsigned short* __restrict__ zib,
    float* __restrict__ out)
{
    __shared__ float num[128][65];   // +1 pad word: bank = (dl + k) % 32
    __shared__ float den[128];
    __shared__ float s2s[128];

    const int b = blockIdx.x, t = threadIdx.x;
    const int n0 = b << BSHIFT;

    for (int i = t; i < 128 * 65; i += 512) (&num[0][0])[i] = 0.f;
    if (t < 128) {
        den[t] = 0.f;
        int node = n0 + t;
        s2s[t] = (node < N_NODES) ? s2[node] : 0.f;
    }
    __syncthreads();

    const int base = b * CAP;
    const int cnt = min(gcur[b], CAP);

    for (int i0 = 0; i0 < cnt; i0 += 512) {
        int i = i0 + t;
        if (i < cnt) {
            uint2 p = payA[base + i];
            int srcn = p.x & 0x1FFFF;
            int dl   = (p.x >> 17) & 127;
            // issue all z-row loads first (8 x 16B); the memory-clobbered
            // ds_add asm sequence below must not pin them behind adds
            const uint4* zp = (const uint4*)(zb + (size_t)srcn * OUT_D);
            uint4 q0 = zp[0], q1 = zp[1], q2 = zp[2], q3 = zp[3];
            uint4 q4 = zp[4], q5 = zp[5], q6 = zp[6], q7 = zp[7];
            float a  = __uint_as_float(p.y) + s1[srcn] + s2s[dl];
            float e  = (a > 0.f) ? a : 0.01f * a;
            float ex = __expf(e);
            float* nrow = num[dl];
            lds_fadd(&den[dl], ex);
            #define ACC2(w, k) { float2 f = up2(w);                 \
                lds_fadd(nrow + (k),     ex * f.x);                 \
                lds_fadd(nrow + (k) + 1, ex * f.y); }
            ACC2(q0.x,  0) ACC2(q0.y,  2) ACC2(q0.z,  4) ACC2(q0.w,  6)
            ACC2(q1.x,  8) ACC2(q1.y, 10) ACC2(q1.z, 12) ACC2(q1.w, 14)
            ACC2(q2.x, 16) ACC2(q2.y, 18) ACC2(q2.z, 20) ACC2(q2.w, 22)
            ACC2(q3.x, 24) ACC2(q3.y, 26) ACC2(q3.z, 28) ACC2(q3.w, 30)
            ACC2(q4.x, 32) ACC2(q4.y, 34) ACC2(q4.z, 36) ACC2(q4.w, 38)
            ACC2(q5.x, 40) ACC2(q5.y, 42) ACC2(q5.z, 44) ACC2(q5.w, 46)
            ACC2(q6.x, 48) ACC2(q6.y, 50) ACC2(q6.z, 52) ACC2(q6.w, 54)
            ACC2(q7.x, 56) ACC2(q7.y, 58) ACC2(q7.z, 60) ACC2(q7.w, 62)
            #undef ACC2
        }
    }
    __syncthreads();   // waits lgkmcnt(0): all ds_add_f32 committed

    // finalize: 4 threads per node, 16 dims each
    const int n = t >> 2;
    const int node = n0 + n;
    if (node < N_NODES) {
        const int dq = (t & 3) * 16;
        float dn = den[n];
        float inv = (dn > 0.f) ? 1.f / dn : 0.f;   // empty -> relu(zi)
        const float* nr = &num[n][dq];
        const unsigned short* zr = zib + (size_t)node * OUT_D + dq;
        uint4 z0 = *(const uint4*)zr;
        uint4 z1 = *(const uint4*)(zr + 8);
        float* op = out + (size_t)node * OUT_D + dq;
        float2 f; float4 o;
        f = up2(z0.x); o.x = fmaxf(f.x + nr[ 0]*inv, 0.f); o.y = fmaxf(f.y + nr[ 1]*inv, 0.f);
        f = up2(z0.y); o.z = fmaxf(f.x + nr[ 2]*inv, 0.f); o.w = fmaxf(f.y + nr[ 3]*inv, 0.f);
        ((float4*)op)[0] = o;
        f = up2(z0.z); o.x = fmaxf(f.x + nr[ 4]*inv, 0.f); o.y = fmaxf(f.y + nr[ 5]*inv, 0.f);
        f = up2(z0.w); o.z = fmaxf(f.x + nr[ 6]*inv, 0.f); o.w = fmaxf(f.y + nr[ 7]*inv, 0.f);
        ((float4*)op)[1] = o;
        f = up2(z1.x); o.x = fmaxf(f.x + nr[ 8]*inv, 0.f); o.y = fmaxf(f.y + nr[ 9]*inv, 0.f);
        f = up2(z1.y); o.z = fmaxf(f.x + nr[10]*inv, 0.f); o.w = fmaxf(f.y + nr[11]*inv, 0.f);
        ((float4*)op)[2] = o;
        f = up2(z1.z); o.x = fmaxf(f.x + nr[12]*inv, 0.f); o.y = fmaxf(f.y + nr[13]*inv, 0.f);
        f = up2(z1.w); o.z = fmaxf(f.x + nr[14]*inv, 0.f); o.w = fmaxf(f.y + nr[15]*inv, 0.f);
        ((float4*)op)[3] = o;
    }
}

extern "C" void kernel_launch(void* const* d_in, const int* in_sizes, int n_in,
                              void* d_out, int out_size, void* d_ws, size_t ws_size,
                              hipStream_t stream) {
    const float* node_feats = (const float*)d_in[0];
    const float* edge_d     = (const float*)d_in[1];
    const float* W0         = (const float*)d_in[2];
    const float* W1         = (const float*)d_in[3];
    const float* W2         = (const float*)d_in[4];
    const float* Wa         = (const float*)d_in[5];
    const int*   src        = (const int*)d_in[6];
    const int*   dst        = (const int*)d_in[7];
    float* out = (float*)d_out;

    // workspace layout (~42.5 MB), 16 B aligned sections
    char* ws = (char*)d_ws;
    uint2* payA = (uint2*)ws;    ws += (size_t)NBUCK * CAP * 8;   // 16.0 MB
    unsigned short* zbuf = (unsigned short*)ws; ws += (size_t)N_NODES * OUT_D * 2;
    unsigned short* zib  = (unsigned short*)ws; ws += (size_t)N_NODES * OUT_D * 2;
    float* s1 = (float*)ws;      ws += (size_t)N_NODES * 4;
    float* s2 = (float*)ws;      ws += (size_t)N_NODES * 4;
    int*   gcur = (int*)ws;      ws += ((NBUCK + 3) & ~3) * 4;

    hipMemsetAsync(gcur, 0, NBUCK * 4, stream);

    fusedA_kernel<<<NBLK_E + NBLK_G, 256, 0, stream>>>(
        node_feats, W1, W2, W0, Wa, dst, src, edge_d,
        gcur, payA, zbuf, zib, s1, s2);

    accum_finalize_kernel<<<NBUCK, 512, 0, stream>>>(
        gcur, payA, s1, s2, zbuf, zib, out);
}

// Round 3
// 185.751 us; speedup vs baseline: 3.6889x; 3.6766x over previous
//
#include <hip/hip_runtime.h>

#define N_NODES 100000
#define N_EDGES 1250000
#define IN_D 128
#define OUT_D 64
#define BSHIFT 7                                  // 128 nodes per bucket
#define NBUCK  782                                // ceil(100000/128)
#define CAP    2560                               // mean 1600 + 24 sigma
#define EPB    4096                               // edges per passA block
#define NBLK_E 306                                // ceil(1250000/4096)
#define NBLK_G 1563                               // ceil(6250 node-tiles / 4)

typedef __attribute__((ext_vector_type(8))) __bf16 bf16x8;
typedef __attribute__((ext_vector_type(4))) float floatx4;

__device__ __forceinline__ float2 up2(unsigned u) {   // 2 bf16 -> 2 f32
    return make_float2(__uint_as_float(u << 16),
                       __uint_as_float(u & 0xFFFF0000u));
}

// ---- Kernel A (fused): blocks [0,306): passA bucket scatter (int4 MLP,
//      fixed-capacity buckets, payload {src|(d&127)<<17, tc*edge_d}).
//      blocks [306,...): node_proj MFMA GEMM, vectorized in-reg W swizzle. ----
__global__ __launch_bounds__(256) void fusedA_kernel(
    const float* __restrict__ x, const float* __restrict__ W1,
    const float* __restrict__ W2, const float* __restrict__ W0,
    const float* __restrict__ Wa,
    const int* __restrict__ dst, const int* __restrict__ src,
    const float* __restrict__ edge_d,
    int* __restrict__ gcur, uint2* __restrict__ payA,
    unsigned short* __restrict__ zb, unsigned short* __restrict__ zib,
    float* __restrict__ s1, float* __restrict__ s2)
{
    __shared__ __bf16 sB[16384];     // 32 KB (GEMM path)
    __shared__ float  sWa[128];
    __shared__ int    h[NBUCK];      // passA path (3.1 KB)
    __shared__ int    lcur[NBUCK];   // (3.1 KB)

    const int t = threadIdx.x;

    if (blockIdx.x < NBLK_E) {
        // ---------------- passA ----------------
        const float tc = W0[0] * Wa[2 * OUT_D];
        for (int i = t; i < NBUCK; i += 256) h[i] = 0;
        __syncthreads();
        const int base = blockIdx.x * EPB;
        for (int k0 = 0; k0 < EPB; k0 += 1024) {
            int i = base + k0 + t * 4;
            if (i < N_EDGES) {                    // N_EDGES % 4 == 0
                int4 d4 = *(const int4*)(dst + i);
                atomicAdd(&h[d4.x >> BSHIFT], 1);
                atomicAdd(&h[d4.y >> BSHIFT], 1);
                atomicAdd(&h[d4.z >> BSHIFT], 1);
                atomicAdd(&h[d4.w >> BSHIFT], 1);
            }
        }
        __syncthreads();
        for (int b = t; b < NBUCK; b += 256) {
            int hc = h[b];
            int p = hc ? atomicAdd(&gcur[b], hc) : 0;
            lcur[b] = b * CAP + p;
        }
        __syncthreads();
        #define EMIT(dv, sv, ev)                                              \
            { int bk = (dv) >> BSHIFT;                                        \
              int pos = atomicAdd(&lcur[bk], 1);                              \
              if (pos < (bk + 1) * CAP)                                       \
                  payA[pos] = make_uint2((unsigned)(sv) |                     \
                                         ((unsigned)((dv) & 127) << 17),      \
                                         __float_as_uint(tc * (ev))); }
        for (int k0 = 0; k0 < EPB; k0 += 1024) {
            int i = base + k0 + t * 4;
            if (i < N_EDGES) {
                int4   d4 = *(const int4*)(dst + i);
                int4   s4 = *(const int4*)(src + i);
                float4 e4 = *(const float4*)(edge_d + i);
                EMIT(d4.x, s4.x, e4.x);
                EMIT(d4.y, s4.y, e4.y);
                EMIT(d4.z, s4.z, e4.z);
                EMIT(d4.w, s4.w, e4.w);
            }
        }
        #undef EMIT
        return;
    }

    // ------- node_proj: vectorized W swizzle (8 groups/thread) -------
    #pragma unroll
    for (int g = 0; g < 8; ++g) {
        int gi = t + g * 256;            // 0..2047
        int n  = gi >> 4;
        int k8 = gi & 15;
        const float* wrow = (n < 64) ? (W1 + n * 128) : (W2 + (n - 64) * 128);
        float4 v0 = *(const float4*)(wrow + k8 * 8);
        float4 v1 = *(const float4*)(wrow + k8 * 8 + 4);
        int lane = ((k8 & 3) << 4) | (n & 15);
        int off  = (((n >> 4) * 4 + (k8 >> 2)) * 64 + lane) * 8;
        bf16x8 bb;
        bb[0] = (__bf16)v0.x; bb[1] = (__bf16)v0.y;
        bb[2] = (__bf16)v0.z; bb[3] = (__bf16)v0.w;
        bb[4] = (__bf16)v1.x; bb[5] = (__bf16)v1.y;
        bb[6] = (__bf16)v1.z; bb[7] = (__bf16)v1.w;
        *(bf16x8*)(sB + off) = bb;
    }
    if (t < 128) sWa[t] = Wa[t];
    __syncthreads();

    const int lane = t & 63;
    const int wave = t >> 6;
    const int tile = (blockIdx.x - NBLK_E) * 4 + wave;
    if (tile * 16 >= N_NODES) return;          // 100000 % 16 == 0

    const int n0 = tile * 16;
    const int m  = lane & 15;
    const int kb = lane >> 4;

    floatx4 acc[8];
    #pragma unroll
    for (int q = 0; q < 8; ++q) acc[q] = (floatx4)(0.f);

    const float* xrow = x + (size_t)(n0 + m) * IN_D;

    #pragma unroll
    for (int kc = 0; kc < 4; ++kc) {
        float4 v0 = *(const float4*)(xrow + kc * 32 + kb * 8);
        float4 v1 = *(const float4*)(xrow + kc * 32 + kb * 8 + 4);
        float xs[8] = {v0.x, v0.y, v0.z, v0.w, v1.x, v1.y, v1.z, v1.w};
        bf16x8 ahi, alo;
        #pragma unroll
        for (int j = 0; j < 8; ++j) {
            __bf16 hh = (__bf16)xs[j];
            ahi[j] = hh;
            alo[j] = (__bf16)(xs[j] - (float)hh);
        }
        #pragma unroll
        for (int nt = 0; nt < 8; ++nt) {
            int off = ((nt * 4 + kc) * 64 + lane) * 8;
            bf16x8 b = *(const bf16x8*)(sB + off);
            acc[nt] = __builtin_amdgcn_mfma_f32_16x16x32_bf16(ahi, b, acc[nt], 0, 0, 0);
            acc[nt] = __builtin_amdgcn_mfma_f32_16x16x32_bf16(alo, b, acc[nt], 0, 0, 0);
        }
    }

    // D layout: col = lane&15 (=m), row = kb*4 + reg
    #pragma unroll
    for (int nt = 0; nt < 8; ++nt) {
        int col = (nt & 3) * 16 + m;
        unsigned short* dp = (nt < 4) ? zb : zib;
        #pragma unroll
        for (int reg = 0; reg < 4; ++reg) {
            int row = n0 + kb * 4 + reg;
            __bf16 hh = (__bf16)acc[nt][reg];
            dp[(size_t)row * OUT_D + col] = *(unsigned short*)&hh;
        }
    }

    // s1[n] = z[n,:].Wa[0:64], s2[n] = z[n,:].Wa[64:128]  (fp32 accs)
    #pragma unroll
    for (int reg = 0; reg < 4; ++reg) {
        float p1 = 0.f, p2 = 0.f;
        #pragma unroll
        for (int nt = 0; nt < 4; ++nt) {
            float zv = acc[nt][reg];
            p1 += zv * sWa[nt * 16 + m];
            p2 += zv * sWa[64 + nt * 16 + m];
        }
        #pragma unroll
        for (int off = 8; off > 0; off >>= 1) {
            p1 += __shfl_xor(p1, off);
            p2 += __shfl_xor(p2, off);
        }
        if (m == 0) {
            int row = n0 + kb * 4 + reg;
            s1[row] = p1;
            s2[row] = p2;
        }
    }
}

// ---- Kernel B (sort+gather): one block per 128-node bucket. In-LDS counting
//      sort of the bucket's payA entries by dst-low (2 native int LDS atomics
//      per edge -- NOT 65 f32 atomics: LDS atomics serialize at ~4 cyc/lane,
//      measured r1/r2), then r0's register-accumulating per-node gather with
//      the edge list served from LDS. No passB launch, no payB HBM trip. ----
__global__ __launch_bounds__(512) void sortgather_kernel(
    const int* __restrict__ gcur, const uint2* __restrict__ payA,
    const float* __restrict__ s1, const float* __restrict__ s2,
    const unsigned short* __restrict__ zb, const unsigned short* __restrict__ zib,
    float* __restrict__ out)
{
    __shared__ uint2 sorted[CAP];    // 20.5 KB
    __shared__ int   h[128];         // per-node degree
    __shared__ int   st[128];        // per-node start (exclusive scan)
    __shared__ int   lc[128];        // scatter cursor
    __shared__ float s2s[128];
    __shared__ uint2 buf[16][32];    // per-(wave,half) {src, ex} staging, 4 KB

    const int b = blockIdx.x, t = threadIdx.x;
    const int n0 = b << BSHIFT;
    const int base = b * CAP;
    const int cnt = min(gcur[b], CAP);

    if (t < 128) {
        h[t] = 0;
        int node = n0 + t;
        s2s[t] = (node < N_NODES) ? s2[node] : 0.f;
    }
    __syncthreads();

    // phase 1: per-node histogram (1 native ds_add per edge)
    for (int i = t; i < cnt; i += 512) {
        uint2 p = payA[base + i];
        atomicAdd(&h[(p.x >> 17) & 127], 1);
    }
    __syncthreads();

    // phase 2: exclusive scan of 128 bins (Hillis-Steele, uniform barriers)
    int v = 0;
    if (t < 128) { v = h[t]; st[t] = v; }
    for (int off = 1; off < 128; off <<= 1) {
        __syncthreads();
        int add = (t < 128 && t >= off) ? st[t - off] : 0;
        __syncthreads();
        if (t < 128) st[t] += add;
    }
    __syncthreads();
    if (t < 128) { int s = st[t] - v; st[t] = s; lc[t] = s; }
    __syncthreads();

    // phase 3: scatter into per-node contiguous runs in LDS (payA re-read is
    // L2-hot; 1 ds_add_rtn + 1 ds_write_b64 per edge)
    for (int i = t; i < cnt; i += 512) {
        uint2 p = payA[base + i];
        int dl = (p.x >> 17) & 127;
        int pos = atomicAdd(&lc[dl], 1);
        sorted[pos] = make_uint2(p.x & 0x1FFFFu, p.y);
    }
    __syncthreads();

    // phase 4: per-node gather/accumulate (r0 structure; 2 nodes per wave,
    // 32 lanes each; 8 rounds cover the 128 nodes). No barriers inside.
    const int lane = t & 63;
    const int wave = t >> 6;
    const int half = lane >> 5;
    const int lh   = lane & 31;
    const int slot = wave * 2 + half;          // 0..15
    const int eC = lh >> 3;                    // edge slot (0..3)
    const int c  = lh & 7;                     // feature chunk

    for (int r = 0; r < 8; ++r) {
        const int ln   = slot + r * 16;        // 0..127
        const int node = n0 + ln;
        const int beg  = st[ln];
        const int len  = h[ln];
        const float s2d = s2s[ln];

        float den = 0.f;
        float2 a0 = make_float2(0.f, 0.f), a1 = a0, a2 = a0, a3 = a0;

        for (int o = 0; o < len; o += 32) {
            int rem = len - o;
            bool vv = lh < rem;
            uint2 p = sorted[beg + o + (vv ? lh : 0)];
            float ex = 0.f;
            if (vv) {
                float a = __uint_as_float(p.y) + s1[p.x] + s2d;
                float e = (a > 0.f) ? a : 0.01f * a;
                ex = __expf(e);
                buf[slot][lh] = make_uint2(p.x, __float_as_uint(ex));
            }
            den += ex;
            // same-wave LDS write->read: hardware-ordered

            int cnt2 = min(32, rem);
            for (int g = 0; g * 4 < cnt2; ++g) {
                int j = g * 4 + eC;
                uint2 pe = buf[slot][(j < cnt2) ? j : 0];
                float exe = (j < cnt2) ? __uint_as_float(pe.y) : 0.f;
                uint4 zv = *(const uint4*)(zb + (size_t)pe.x * OUT_D + c * 8);
                float2 w0 = up2(zv.x), w1 = up2(zv.y), w2 = up2(zv.z), w3 = up2(zv.w);
                a0.x = fmaf(exe, w0.x, a0.x); a0.y = fmaf(exe, w0.y, a0.y);
                a1.x = fmaf(exe, w1.x, a1.x); a1.y = fmaf(exe, w1.y, a1.y);
                a2.x = fmaf(exe, w2.x, a2.x); a2.y = fmaf(exe, w2.y, a2.y);
                a3.x = fmaf(exe, w3.x, a3.x); a3.y = fmaf(exe, w3.y, a3.y);
            }
        }

        // reductions within each 32-lane half
        #pragma unroll
        for (int off = 16; off > 0; off >>= 1) den += __shfl_xor(den, off);
        #pragma unroll
        for (int off = 8; off <= 16; off <<= 1) {
            a0.x += __shfl_xor(a0.x, off); a0.y += __shfl_xor(a0.y, off);
            a1.x += __shfl_xor(a1.x, off); a1.y += __shfl_xor(a1.y, off);
            a2.x += __shfl_xor(a2.x, off); a2.y += __shfl_xor(a2.y, off);
            a3.x += __shfl_xor(a3.x, off); a3.y += __shfl_xor(a3.y, off);
        }

        if (lh < 8 && node < N_NODES) {
            float inv = (den > 0.f) ? 1.f / den : 0.f;   // empty -> relu(zi)
            uint4 zv = *(const uint4*)(zib + (size_t)node * OUT_D + lh * 8);
            float2 w0 = up2(zv.x), w1 = up2(zv.y), w2 = up2(zv.z), w3 = up2(zv.w);
            float4 o0, o1;
            o0.x = fmaxf(w0.x + a0.x * inv, 0.f);
            o0.y = fmaxf(w0.y + a0.y * inv, 0.f);
            o0.z = fmaxf(w1.x + a1.x * inv, 0.f);
            o0.w = fmaxf(w1.y + a1.y * inv, 0.f);
            o1.x = fmaxf(w2.x + a2.x * inv, 0.f);
            o1.y = fmaxf(w2.y + a2.y * inv, 0.f);
            o1.z = fmaxf(w3.x + a3.x * inv, 0.f);
            o1.w = fmaxf(w3.y + a3.y * inv, 0.f);
            *(float4*)(out + (size_t)node * OUT_D + lh * 8)     = o0;
            *(float4*)(out + (size_t)node * OUT_D + lh * 8 + 4) = o1;
        }
    }
}

extern "C" void kernel_launch(void* const* d_in, const int* in_sizes, int n_in,
                              void* d_out, int out_size, void* d_ws, size_t ws_size,
                              hipStream_t stream) {
    const float* node_feats = (const float*)d_in[0];
    const float* edge_d     = (const float*)d_in[1];
    const float* W0         = (const float*)d_in[2];
    const float* W1         = (const float*)d_in[3];
    const float* W2         = (const float*)d_in[4];
    const float* Wa         = (const float*)d_in[5];
    const int*   src        = (const int*)d_in[6];
    const int*   dst        = (const int*)d_in[7];
    float* out = (float*)d_out;

    // workspace layout (~26.5 MB), 16 B aligned sections
    char* ws = (char*)d_ws;
    uint2* payA = (uint2*)ws;    ws += (size_t)NBUCK * CAP * 8;   // 16.0 MB
    unsigned short* zbuf = (unsigned short*)ws; ws += (size_t)N_NODES * OUT_D * 2;
    unsigned short* zib  = (unsigned short*)ws; ws += (size_t)N_NODES * OUT_D * 2;
    float* s1 = (float*)ws;      ws += (size_t)N_NODES * 4;
    float* s2 = (float*)ws;      ws += (size_t)N_NODES * 4;
    int*   gcur = (int*)ws;      ws += ((NBUCK + 3) & ~3) * 4;

    hipMemsetAsync(gcur, 0, NBUCK * 4, stream);

    fusedA_kernel<<<NBLK_E + NBLK_G, 256, 0, stream>>>(
        node_feats, W1, W2, W0, Wa, dst, src, edge_d,
        gcur, payA, zbuf, zib, s1, s2);

    sortgather_kernel<<<NBUCK, 512, 0, stream>>>(
        gcur, payA, s1, s2, zbuf, zib, out);
}